// Round 6
// baseline (288.500 us; speedup 1.0000x reference)
//
#include <hip/hip_runtime.h>
#include <math.h>

#define B_ 32
#define N_ 64
#define K_ 128
#define NPAIR (B_*N_*N_)
#define PREP_TOTAL 733184

typedef __attribute__((ext_vector_type(8))) short short8;
typedef __attribute__((ext_vector_type(8))) __bf16 bf16x8;
typedef __attribute__((ext_vector_type(4))) float floatx4;

__device__ __forceinline__ float silu_f(float x) {
    return x / (1.0f + expf(-x));
}

__device__ __forceinline__ short f2bf(float x) {
    union { float f; unsigned u; } v; v.f = x;
    unsigned r = (v.u + 0x7FFFu + ((v.u >> 16) & 1u)) >> 16;
    return (short)r;
}
__device__ __forceinline__ float bf2f(short s) {
    union { unsigned u; float f; } v;
    v.u = ((unsigned)(unsigned short)s) << 16;
    return v.f;
}
__device__ __forceinline__ bf16x8 ld_frag(const short* p) {
    short8 r = *(const short8*)p;
    return __builtin_bit_cast(bf16x8, r);
}

// ---------------------------------------------------------------------------
// Kernel 0: weight prep -> bf16 transposed layouts (B-operand: BT[n][k])
// short offsets:
//   0       r1w1T [64][64]
//   4096    r1w2T [64][64]
//   8192    r2w1T [64][64]
//   12288   r2w2T [64][64]
//   16384   r2w3T [256][64]
//   32768   wT0   [512][704] (zero-pad k>=641)
//   393216  wT1   [512][512]
//   655360  w0T_1 [64][32]  (r1w0^T zero-pad k>=8)
//   657408  w0T_2 [64][32]  (r2w0^T zero-pad k>=8)
//   659456  w3T_1 [384][64] (r1w3^T)
//   684032  lcatT [384][128] ([l0|l1|l2]^T concat along n)
//   733184  end
// ---------------------------------------------------------------------------
__global__ __launch_bounds__(256) void prep_kernel(
    const float* __restrict__ r1w1, const float* __restrict__ r1w2,
    const float* __restrict__ r2w1, const float* __restrict__ r2w2,
    const float* __restrict__ r2w3, const float* __restrict__ mw0,
    const float* __restrict__ mw1,
    const float* __restrict__ r1w0, const float* __restrict__ r2w0,
    const float* __restrict__ r1w3,
    const float* __restrict__ l0, const float* __restrict__ l1,
    const float* __restrict__ l2,
    short* __restrict__ dst)
{
    int idx = blockIdx.x * 256 + threadIdx.x;
    if (idx >= PREP_TOTAL) return;
    short v;
    if (idx < 4096) {
        int h = idx >> 6, k = idx & 63; v = f2bf(r1w1[k*64 + h]);
    } else if (idx < 8192) {
        int i = idx - 4096; int h = i >> 6, k = i & 63; v = f2bf(r1w2[k*64 + h]);
    } else if (idx < 12288) {
        int i = idx - 8192; int h = i >> 6, k = i & 63; v = f2bf(r2w1[k*64 + h]);
    } else if (idx < 16384) {
        int i = idx - 12288; int h = i >> 6, k = i & 63; v = f2bf(r2w2[k*64 + h]);
    } else if (idx < 32768) {
        int i = idx - 16384; int col = i >> 6, h = i & 63; v = f2bf(r2w3[h*256 + col]);
    } else if (idx < 393216) {
        int i = idx - 32768; int n = i / 704, k = i - n*704;
        v = (k < 641) ? f2bf(mw0[(size_t)k*512 + n]) : (short)0;
    } else if (idx < 655360) {
        int i = idx - 393216; int n = i >> 9, k = i & 511;
        v = f2bf(mw1[(size_t)k*512 + n]);
    } else if (idx < 657408) {
        int i = idx - 655360; int h = i >> 5, k = i & 31;
        v = (k < 8) ? f2bf(r1w0[k*64 + h]) : (short)0;
    } else if (idx < 659456) {
        int i = idx - 657408; int h = i >> 5, k = i & 31;
        v = (k < 8) ? f2bf(r2w0[k*64 + h]) : (short)0;
    } else if (idx < 684032) {
        int i = idx - 659456; int col = i >> 6, h = i & 63;
        v = f2bf(r1w3[(size_t)h*384 + col]);
    } else {
        int i = idx - 684032; int n = i >> 7, k = i & 127;
        float src = (n < 128) ? l0[(size_t)k*128 + n]
                  : (n < 256) ? l1[(size_t)k*128 + (n-128)]
                              : l2[(size_t)k*128 + (n-256)];
        v = f2bf(src);
    }
    dst[idx] = v;
}

// ---------------------------------------------------------------------------
// MFMA MLP layer helpers (1 row-tile per wave, 4 waves = 64 rows).
// src [64][72] bf16 LDS; WT [64n][64k] bf16 global; silu epilogue.
// ---------------------------------------------------------------------------
__device__ __forceinline__ void mfma_layer(
    const short* __restrict__ src, const short* __restrict__ WT,
    const float* __restrict__ bias, short* __restrict__ dst,
    int wv, int qd, int nn)
{
    floatx4 acc[4];
    #pragma unroll
    for (int tt = 0; tt < 4; tt++) acc[tt] = (floatx4){0.f, 0.f, 0.f, 0.f};
    #pragma unroll
    for (int ks = 0; ks < 64; ks += 32) {
        bf16x8 a = ld_frag(&src[(wv*16 + nn)*72 + ks + qd*8]);
        #pragma unroll
        for (int tt = 0; tt < 4; tt++) {
            bf16x8 b = ld_frag(&WT[(tt*16 + nn)*64 + ks + qd*8]);
            acc[tt] = __builtin_amdgcn_mfma_f32_16x16x32_bf16(a, b, acc[tt], 0, 0, 0);
        }
    }
    #pragma unroll
    for (int tt = 0; tt < 4; tt++) {
        int col = tt*16 + nn;
        float bv = bias[col];
        #pragma unroll
        for (int i = 0; i < 4; i++) {
            int row = wv*16 + qd*4 + i;
            dst[row*72 + col] = f2bf(silu_f(acc[tt][i] + bv));
        }
    }
}

// Writes dst TRANSPOSED: dstT[col][row] (ld 72)
__device__ __forceinline__ void mfma_layer_T(
    const short* __restrict__ src, const short* __restrict__ WT,
    const float* __restrict__ bias, short* __restrict__ dstT,
    int wv, int qd, int nn)
{
    floatx4 acc[4];
    #pragma unroll
    for (int tt = 0; tt < 4; tt++) acc[tt] = (floatx4){0.f, 0.f, 0.f, 0.f};
    #pragma unroll
    for (int ks = 0; ks < 64; ks += 32) {
        bf16x8 a = ld_frag(&src[(wv*16 + nn)*72 + ks + qd*8]);
        #pragma unroll
        for (int tt = 0; tt < 4; tt++) {
            bf16x8 b = ld_frag(&WT[(tt*16 + nn)*64 + ks + qd*8]);
            acc[tt] = __builtin_amdgcn_mfma_f32_16x16x32_bf16(a, b, acc[tt], 0, 0, 0);
        }
    }
    #pragma unroll
    for (int tt = 0; tt < 4; tt++) {
        int col = tt*16 + nn;
        float bv = bias[col];
        #pragma unroll
        for (int i = 0; i < 4; i++) {
            int row = wv*16 + qd*4 + i;
            dstT[col*72 + row] = f2bf(silu_f(acc[tt][i] + bv));
        }
    }
}

// Writes to GLOBAL dst (row stride 64): hc2 output layer.
__device__ __forceinline__ void mfma_layer_gout(
    const short* __restrict__ src, const short* __restrict__ WT,
    const float* __restrict__ bias, short* __restrict__ gdst,
    int wv, int qd, int nn)
{
    floatx4 acc[4];
    #pragma unroll
    for (int tt = 0; tt < 4; tt++) acc[tt] = (floatx4){0.f, 0.f, 0.f, 0.f};
    #pragma unroll
    for (int ks = 0; ks < 64; ks += 32) {
        bf16x8 a = ld_frag(&src[(wv*16 + nn)*72 + ks + qd*8]);
        #pragma unroll
        for (int tt = 0; tt < 4; tt++) {
            bf16x8 b = ld_frag(&WT[(tt*16 + nn)*64 + ks + qd*8]);
            acc[tt] = __builtin_amdgcn_mfma_f32_16x16x32_bf16(a, b, acc[tt], 0, 0, 0);
        }
    }
    #pragma unroll
    for (int tt = 0; tt < 4; tt++) {
        int col = tt*16 + nn;
        float bv = bias[col];
        #pragma unroll
        for (int i = 0; i < 4; i++) {
            int row = wv*16 + qd*4 + i;
            gdst[row*64 + col] = f2bf(silu_f(acc[tt][i] + bv));
        }
    }
}

// L0 (K=32): rad_bf[64][32] @ w0T[64][32] -> silu -> act[64][72]
__device__ __forceinline__ void mfma_layer0(
    const short* __restrict__ rad_bf, const short* __restrict__ w0T,
    const float* __restrict__ b0, short* __restrict__ dst,
    int wv, int qd, int nn)
{
    floatx4 acc[4];
    #pragma unroll
    for (int tt = 0; tt < 4; tt++) acc[tt] = (floatx4){0.f, 0.f, 0.f, 0.f};
    bf16x8 a = ld_frag(&rad_bf[(wv*16 + nn)*32 + qd*8]);
    #pragma unroll
    for (int tt = 0; tt < 4; tt++) {
        bf16x8 b = ld_frag(&w0T[(tt*16 + nn)*32 + qd*8]);
        acc[tt] = __builtin_amdgcn_mfma_f32_16x16x32_bf16(a, b, acc[tt], 0, 0, 0);
    }
    #pragma unroll
    for (int tt = 0; tt < 4; tt++) {
        int col = tt*16 + nn;
        float bv = b0[col];
        #pragma unroll
        for (int i = 0; i < 4; i++) {
            int row = wv*16 + qd*4 + i;
            dst[row*72 + col] = f2bf(silu_f(acc[tt][i] + bv));
        }
    }
}

// ---------------------------------------------------------------------------
// Kernel 1 (pass1x): one block per node. Fuses: geometry (64 pairs in-block,
// rad never hits global), BOTH radial MLPs (r1 chain + r2 chain interleaved
// per stage for ILP; hc2 -> global for pass2b), and the pass-1 back half
// (G, msg, q, A2, P, s1/v1/h1/feats).
// LDS (41472 B -> 3 blocks/CU):
//   actA [0,9216)        r1 L0/L2T out; late: A2 [16][136]
//   actB [9216,18432)    r1 L1 out; late: msg [9][128] f32 + q_s + Psa/Psb
//   actC [18432,27648)   r2 L0 out
//   actD [27648,36864)   r2 L1 out
//   R2   [36864,41472)   rad_bf [64][32] / Ym_bf [16][72] (+SY pads) + G_bf
// ---------------------------------------------------------------------------
__global__ __launch_bounds__(256) void pass1x_kernel(
    const float* __restrict__ pos, const float* __restrict__ cell,
    const float* __restrict__ wemb,
    const short* __restrict__ w0T1, const float* __restrict__ b01,
    const short* __restrict__ w1T1, const float* __restrict__ b11,
    const short* __restrict__ w2T1, const float* __restrict__ b21,
    const short* __restrict__ w3T1, const float* __restrict__ b31,
    const short* __restrict__ w0T2, const float* __restrict__ b02,
    const short* __restrict__ w1T2, const float* __restrict__ b12,
    const short* __restrict__ w2T2, const float* __restrict__ b22,
    const short* __restrict__ lcatT, const float* __restrict__ timeg,
    float* __restrict__ geo4, short* __restrict__ hc2,
    float* __restrict__ h1g, float* __restrict__ v1g, short* __restrict__ featsb)
{
    __shared__ __align__(16) char smem[41472];
    short* actA   = (short*)smem;                   // [64][72]
    short* actB   = (short*)(smem + 9216);          // [64][72]
    short* actC   = (short*)(smem + 18432);         // [64][72]
    short* actD   = (short*)(smem + 27648);         // [64][72]
    float* msg    = (float*)(smem + 9216);          // alias actB: [9][128]
    float* q_s    = (float*)(smem + 9216 + 4608);   // [128]
    short* rad_bf = (short*)(smem + 36864);         // [64][32]
    short* Ym_bf  = (short*)(smem + 36864);         // alias: [16][72], SY in pads
    short* G_bf   = (short*)(smem + 36864 + 2304);  // [16][72]
    short* A2     = (short*)smem;                   // alias actA: [16][136]
    float* Psa    = (float*)(smem + 9216);          // alias msg
    float* Psb    = Psa + 128;

    int t = threadIdx.x;
    int wv = t >> 6, lane = t & 63, qd = lane >> 4, nn = lane & 15;
    int node = blockIdx.x;
    int b = node >> 6;
    int irow = node & 63;
    size_t pbase = (size_t)node * 64;

    // ---- S1: geometry for pair (irow, j=t) by wave 0; rad -> LDS bf16;
    //          geo4 (mask,Y1) -> global for pass2b; SY shuffle-reduce ----
    float vals[9];
    float sy9[9];
    if (t < 64) {
        int j = t;
        const float* pi = pos + (size_t)(b*N_ + irow)*3;
        const float* pj = pos + (size_t)(b*N_ + j)*3;
        float d0 = pi[0]-pj[0], d1 = pi[1]-pj[1], d2 = pi[2]-pj[2];
        d0 -= rintf(d0); d1 -= rintf(d1); d2 -= rintf(d2);
        const float* C = cell + b*9;
        float dc0 = d0*C[0] + d1*C[3] + d2*C[6];
        float dc1 = d0*C[1] + d1*C[4] + d2*C[7];
        float dc2 = d0*C[2] + d1*C[5] + d2*C[8];
        float r2 = fmaxf(dc0*dc0 + dc1*dc1 + dc2*dc2, 1e-12f);
        float r = sqrtf(r2);
        bool m = (r < 5.0f) && (irow != j);
        float mf = m ? 1.0f : 0.0f;
        float rs = m ? r : 1.0f;
        float inv_rs = 1.0f / rs;
        float x = dc0*inv_rs*mf, y = dc1*inv_rs*mf, z = dc2*inv_rs*mf;
        float u = r * 0.2f;
        float u2 = u*u, u4 = u2*u2, u5 = u4*u;
        float fc = 1.0f - 21.0f*u5 + 35.0f*u5*u - 15.0f*u5*u2;
        fc = (u < 1.0f) ? fc : 0.0f;
        float pref = 0.6324555320336759f * inv_rs * (fc * mf);
        float w = 0.6283185307179586f * rs;
        float sw = sinf(w), cw = cosf(w);
        float twoc = 2.0f * cw;
        float sm = 0.0f, s = sw;
        #pragma unroll
        for (int n = 0; n < 8; n++) {
            rad_bf[j*32 + n] = f2bf(pref * s);
            float nx = twoc*s - sm;
            sm = s; s = nx;
        }
        #pragma unroll
        for (int k = 8; k < 32; k++) rad_bf[j*32 + k] = 0;
        const float s3  = 1.7320508075688772f;
        const float s5  = 2.23606797749979f;
        const float s15 = 3.872983346207417f;
        vals[0] = mf;
        vals[1] = s3*x; vals[2] = s3*y; vals[3] = s3*z;
        vals[4] = s15*x*y;
        vals[5] = s15*y*z;
        vals[6] = 0.5f*s5*(3.0f*z*z - 1.0f);
        vals[7] = s15*x*z;
        vals[8] = 0.5f*s15*(x*x - y*y);
        *(float4*)&geo4[(pbase + j)*4] = make_float4(mf, vals[1], vals[2], vals[3]);
        #pragma unroll
        for (int m9 = 0; m9 < 9; m9++) {
            float sv = vals[m9];
            #pragma unroll
            for (int off = 32; off > 0; off >>= 1) sv += __shfl_xor(sv, off);
            sy9[m9] = sv;
        }
    }
    __syncthreads();

    // ---- S2: L0 (r1) + L0' (r2), both from rad_bf ----
    mfma_layer0(rad_bf, w0T1, b01, actA, wv, qd, nn);
    mfma_layer0(rad_bf, w0T2, b02, actC, wv, qd, nn);
    __syncthreads();

    // ---- S3: write Ym/SY (rad dead); L1 (r1) + L1' (r2) ----
    if (t < 64) {
        int j = t;
        #pragma unroll
        for (int m9 = 0; m9 < 9; m9++) Ym_bf[m9*72 + j] = f2bf(vals[m9]);
        #pragma unroll
        for (int m9 = 9; m9 < 16; m9++) Ym_bf[m9*72 + j] = 0;
        #pragma unroll
        for (int m9 = 0; m9 < 9; m9++)
            if (j == m9) *(float*)(&Ym_bf[m9*72 + 64]) = sy9[m9];
    }
    mfma_layer(actA, w1T1, b11, actB, wv, qd, nn);
    mfma_layer(actC, w1T2, b12, actD, wv, qd, nn);
    __syncthreads();

    // ---- S4: L2 transposed (r1: actB -> actA = hcT) + L2' (r2 -> global hc2) ----
    mfma_layer_T(actB, w2T1, b21, actA, wv, qd, nn);
    mfma_layer_gout(actD, w2T2, b22, hc2 + (size_t)node*4096, wv, qd, nn);
    __syncthreads();

    // ---- S5: G[m][h] = sum_j Ym[m][j]*hc[j][h]; wave wv owns h-tile wv ----
    {
        floatx4 acc = (floatx4){0.f, 0.f, 0.f, 0.f};
        #pragma unroll
        for (int ks = 0; ks < 64; ks += 32) {
            bf16x8 a = ld_frag(&Ym_bf[nn*72 + ks + qd*8]);
            bf16x8 bb = ld_frag(&actA[(wv*16 + nn)*72 + ks + qd*8]);
            acc = __builtin_amdgcn_mfma_f32_16x16x32_bf16(a, bb, acc, 0, 0, 0);
        }
        #pragma unroll
        for (int i = 0; i < 4; i++)
            G_bf[(qd*4 + i)*72 + wv*16 + nn] = f2bf(acc[i]);
    }
    __syncthreads();

    // ---- S6: msg = (G@w3 + SY*b3)*wemb/16  (into actB region) ----
    {
        floatx4 acc[6];
        #pragma unroll
        for (int tt = 0; tt < 6; tt++) acc[tt] = (floatx4){0.f, 0.f, 0.f, 0.f};
        #pragma unroll
        for (int ks = 0; ks < 64; ks += 32) {
            bf16x8 a = ld_frag(&G_bf[nn*72 + ks + qd*8]);
            #pragma unroll
            for (int tt = 0; tt < 6; tt++) {
                bf16x8 bb = ld_frag(&w3T1[((wv*6 + tt)*16 + nn)*64 + ks + qd*8]);
                acc[tt] = __builtin_amdgcn_mfma_f32_16x16x32_bf16(a, bb, acc[tt], 0, 0, 0);
            }
        }
        #pragma unroll
        for (int tt = 0; tt < 6; tt++) {
            int col = (wv*6 + tt)*16 + nn;
            #pragma unroll
            for (int i = 0; i < 4; i++) {
                int m9 = qd*4 + i;
                if (m9 < 9) {
                    int c = (m9 == 0) ? 0 : ((m9 < 4) ? 1 : 2);
                    int k = col - c*128;
                    if (k >= 0 && k < 128) {
                        float sym = *(const float*)(&Ym_bf[m9*72 + 64]);
                        msg[m9*128 + k] = (acc[tt][i] + sym*b31[col]) * wemb[k] * 0.0625f;
                    }
                }
            }
        }
    }
    __syncthreads();

    // ---- S7: q[k] ----
    if (t < 128) {
        int k = t;
        float acc = 0.f;
        #pragma unroll
        for (int m9 = 4; m9 < 9; m9++) { float v = msg[m9*128 + k]; acc += v*v; }
        q_s[k] = acc;
    }
    __syncthreads();

    // ---- S8: A2 rows: 0=msg0, 1=q, 2..4=msg1..3, 5..15=0 (into actA) ----
    for (int idx = t; idx < 2048; idx += 256) {
        int r = idx >> 7, k = idx & 127;
        float v = (r == 0) ? msg[k]
                : (r == 1) ? q_s[k]
                : (r < 5)  ? msg[(r-1)*128 + k] : 0.f;
        A2[r*136 + k] = f2bf(v);
    }
    __syncthreads();

    // ---- S9: P = A2 @ lcatT (N=384, K=128); extract s1 parts + v1 ----
    {
        bf16x8 pa[4];
        #pragma unroll
        for (int ksI = 0; ksI < 4; ksI++)
            pa[ksI] = ld_frag(&A2[nn*136 + ksI*32 + qd*8]);
        floatx4 acc[6];
        #pragma unroll
        for (int tt = 0; tt < 6; tt++) acc[tt] = (floatx4){0.f, 0.f, 0.f, 0.f};
        #pragma unroll
        for (int tt = 0; tt < 6; tt++) {
            int tn = wv*6 + tt;
            #pragma unroll
            for (int ksI = 0; ksI < 4; ksI++) {
                bf16x8 bf = ld_frag(&lcatT[((size_t)(tn*16 + nn))*128 + ksI*32 + qd*8]);
                acc[tt] = __builtin_amdgcn_mfma_f32_16x16x32_bf16(pa[ksI], bf, acc[tt], 0, 0, 0);
            }
        }
        #pragma unroll
        for (int tt = 0; tt < 6; tt++) {
            int n = (wv*6 + tt)*16 + nn;
            #pragma unroll
            for (int i = 0; i < 4; i++) {
                int r = qd*4 + i;
                float val = acc[tt][i];
                if (r == 0 && n < 128) Psa[n] = val;
                else if (r == 1 && n >= 256) Psb[n - 256] = val;
                else if (r >= 2 && r < 5 && n >= 128 && n < 256) {
                    int m9 = r - 2, cc = n - 128;
                    v1g[(size_t)node*384 + m9*128 + cc] = val;
                    featsb[(size_t)node*704 + 128 + m9*128 + cc] = f2bf(val);
                }
            }
        }
    }
    __syncthreads();

    // ---- S10: finalize s1/h1/time/pad ----
    if (t < 128) {
        float s1 = Psa[t] + Psb[t];
        featsb[(size_t)node*704 + t] = f2bf(s1);
        h1g[(size_t)node*128 + t] = silu_f(s1);
    } else if (t == 128) {
        featsb[(size_t)node*704 + 640] = f2bf(timeg[b]);
    } else if (t > 128 && t < 192) {
        featsb[(size_t)node*704 + 640 + (t - 128)] = 0;   // zero K-pad 641..703
    }
}

// ---------------------------------------------------------------------------
// Kernel 2 (pass2b): combine-only. we2 = hc2 @ w3T_2 (A-fragments straight
// from global); combine with h1/inv; msgab; s2. LDS ~1.8 KB -> high occupancy.
// ---------------------------------------------------------------------------
__global__ __launch_bounds__(256) void pass2b_kernel(
    const float* __restrict__ geo4,
    const short* __restrict__ hc2,
    const short* __restrict__ w3T, const float* __restrict__ b3,
    const float* __restrict__ mix2,
    const float* __restrict__ h1g, const float* __restrict__ v1g,
    short* __restrict__ featsb)
{
    __shared__ float mask_s[64];
    __shared__ float Y1s[64*4];
    __shared__ float msgab[128];
    int t = threadIdx.x;
    int wv = t >> 6, lane = t & 63, qd = lane >> 4, nn = lane & 15;
    int node = blockIdx.x;
    int b = node >> 6;
    size_t pbase = (size_t)node * 64;

    if (t < 64) {
        float4 g = *(const float4*)&geo4[(pbase + t)*4];
        mask_s[t] = g.x;
        Y1s[t*4 + 0] = g.y; Y1s[t*4 + 1] = g.z; Y1s[t*4 + 2] = g.w;
    }
    if (t >= 64 && t < 192) msgab[t - 64] = 0.f;
    __syncthreads();

    // we2 = hc2 @ w3 [64x256]; wave wv owns row-tile wv; 4 groups of 4 n-tiles
    const short* hcb = hc2 + (size_t)node*4096;
    bf16x8 a0 = ld_frag(&hcb[(wv*16 + nn)*64 + qd*8]);
    bf16x8 a1 = ld_frag(&hcb[(wv*16 + nn)*64 + 32 + qd*8]);
    for (int g = 0; g < 4; g++) {
        floatx4 acc[4];
        #pragma unroll
        for (int tt = 0; tt < 4; tt++) acc[tt] = (floatx4){0.f, 0.f, 0.f, 0.f};
        #pragma unroll
        for (int tt = 0; tt < 4; tt++) {
            int ct = g*4 + tt;
            bf16x8 b0f = ld_frag(&w3T[(ct*16 + nn)*64 + qd*8]);
            bf16x8 b1f = ld_frag(&w3T[(ct*16 + nn)*64 + 32 + qd*8]);
            acc[tt] = __builtin_amdgcn_mfma_f32_16x16x32_bf16(a0, b0f, acc[tt], 0, 0, 0);
            acc[tt] = __builtin_amdgcn_mfma_f32_16x16x32_bf16(a1, b1f, acc[tt], 0, 0, 0);
        }
        #pragma unroll
        for (int tt = 0; tt < 4; tt++) {
            int col = (g*4 + tt)*16 + nn;
            float bias = b3[col];
            int k = col & 127;
            float p = 0.f;
            if (col < 128) {
                #pragma unroll
                for (int i = 0; i < 4; i++) {
                    int j = wv*16 + qd*4 + i;
                    float we = (acc[tt][i] + bias) * mask_s[j];
                    p += we * h1g[((size_t)b*64 + j)*128 + k];
                }
            } else {
                #pragma unroll
                for (int i = 0; i < 4; i++) {
                    int j = wv*16 + qd*4 + i;
                    float we = (acc[tt][i] + bias) * mask_s[j];
                    const float* vb = &v1g[((size_t)b*64 + j)*384 + k];
                    float inv = Y1s[j*4+0]*vb[0] + Y1s[j*4+1]*vb[128] + Y1s[j*4+2]*vb[256];
                    p += we * inv;
                }
            }
            p += __shfl_xor(p, 16);
            p += __shfl_xor(p, 32);
            if (qd == 0) atomicAdd(&msgab[k], p);
        }
    }
    __syncthreads();

    // s2 = msgab @ mix2 / 16
    if (t < 128) {
        int c = t;
        float acc = 0.f;
        for (int k = 0; k < 128; k++) acc += msgab[k] * mix2[k*128 + c];
        featsb[(size_t)node*704 + 512 + c] = f2bf(acc * 0.0625f);   // s2
    }
}

// ---------------------------------------------------------------------------
// Kernel 3: bf16 MFMA GEMM, C[M][ldo] = relu(A[M][lda] @ WT^T + bias), bf16 out.
// ---------------------------------------------------------------------------
__global__ __launch_bounds__(256) void gemm_mfma_kernel(
    const short* __restrict__ A, int lda,
    const short* __restrict__ BT, int ldb, int K,
    const float* __restrict__ bias, short* __restrict__ Cout, int ldo)
{
    __shared__ short As[64*72];
    __shared__ short Bs[64*72];
    int t = threadIdx.x;
    int wv = t >> 6, lane = t & 63, qd = lane >> 4, nn = lane & 15;
    int m0 = blockIdx.x * 64, n0 = blockIdx.y * 64;
    floatx4 acc[4];
    #pragma unroll
    for (int tt = 0; tt < 4; tt++) acc[tt] = (floatx4){0.f, 0.f, 0.f, 0.f};

    for (int kc = 0; kc < K; kc += 64) {
        for (int s = t; s < 512; s += 256) {
            int j = s >> 3, kk = (s & 7) * 8;
            *(uint4*)&As[j*72 + kk] = *(const uint4*)&A[(size_t)(m0 + j)*lda + kc + kk];
            *(uint4*)&Bs[j*72 + kk] = *(const uint4*)&BT[(size_t)(n0 + j)*ldb + kc + kk];
        }
        __syncthreads();
        #pragma unroll
        for (int ks = 0; ks < 64; ks += 32) {
            bf16x8 a = ld_frag(&As[(wv*16 + nn)*72 + ks + qd*8]);
            #pragma unroll
            for (int tt = 0; tt < 4; tt++) {
                bf16x8 bb = ld_frag(&Bs[(tt*16 + nn)*72 + ks + qd*8]);
                acc[tt] = __builtin_amdgcn_mfma_f32_16x16x32_bf16(a, bb, acc[tt], 0, 0, 0);
            }
        }
        __syncthreads();
    }
    #pragma unroll
    for (int tt = 0; tt < 4; tt++) {
        int n = n0 + tt*16 + nn;
        float bv = bias[n];
        #pragma unroll
        for (int i = 0; i < 4; i++) {
            int m = m0 + wv*16 + qd*4 + i;
            Cout[(size_t)m*ldo + n] = f2bf(fmaxf(acc[tt][i] + bv, 0.f));
        }
    }
}

// ---------------------------------------------------------------------------
// Kernel 4: out[node,3] = H(bf16)[node,512] @ w2[512,3] + b2. One wave/node.
// ---------------------------------------------------------------------------
__global__ __launch_bounds__(64) void final3_kernel(
    const short* __restrict__ H, const float* __restrict__ w2,
    const float* __restrict__ b2, float* __restrict__ out)
{
    int node = blockIdx.x, lane = threadIdx.x;
    float a0 = 0.f, a1 = 0.f, a2 = 0.f;
    #pragma unroll
    for (int r = 0; r < 8; r++) {
        int k = r*64 + lane;
        float h = bf2f(H[(size_t)node*512 + k]);
        a0 += h * w2[k*3 + 0];
        a1 += h * w2[k*3 + 1];
        a2 += h * w2[k*3 + 2];
    }
    #pragma unroll
    for (int off = 32; off > 0; off >>= 1) {
        a0 += __shfl_down(a0, off);
        a1 += __shfl_down(a1, off);
        a2 += __shfl_down(a2, off);
    }
    if (lane == 0) {
        out[(size_t)node*3 + 0] = a0 + b2[0];
        out[(size_t)node*3 + 1] = a1 + b2[1];
        out[(size_t)node*3 + 2] = a2 + b2[2];
    }
}

extern "C" void kernel_launch(void* const* d_in, const int* in_sizes, int n_in,
                              void* d_out, int out_size, void* d_ws, size_t ws_size,
                              hipStream_t stream) {
    const float* pos   = (const float*)d_in[0];
    const float* timeg = (const float*)d_in[1];
    const float* cell  = (const float*)d_in[2];
    const float* wemb  = (const float*)d_in[3];
    const float* r1w0  = (const float*)d_in[4];
    const float* r1b0  = (const float*)d_in[5];
    const float* r1w1  = (const float*)d_in[6];
    const float* r1b1  = (const float*)d_in[7];
    const float* r1w2  = (const float*)d_in[8];
    const float* r1b2  = (const float*)d_in[9];
    const float* r1w3  = (const float*)d_in[10];
    const float* r1b3  = (const float*)d_in[11];
    const float* l0    = (const float*)d_in[12];
    const float* l1    = (const float*)d_in[13];
    const float* l2    = (const float*)d_in[14];
    const float* r2w0  = (const float*)d_in[15];
    const float* r2b0  = (const float*)d_in[16];
    const float* r2w1  = (const float*)d_in[17];
    const float* r2b1  = (const float*)d_in[18];
    const float* r2w2  = (const float*)d_in[19];
    const float* r2b2  = (const float*)d_in[20];
    const float* r2w3  = (const float*)d_in[21];
    const float* r2b3  = (const float*)d_in[22];
    const float* mix2  = (const float*)d_in[23];
    const float* mw0   = (const float*)d_in[24];
    const float* mb0   = (const float*)d_in[25];
    const float* mw1   = (const float*)d_in[26];
    const float* mb1   = (const float*)d_in[27];
    const float* mw2   = (const float*)d_in[28];
    const float* mb2   = (const float*)d_in[29];

    float* ws    = (float*)d_ws;
    float* geo4  = ws;                                   //   524,288 f (NPAIR float4)
    float* h1    = geo4 + (size_t)NPAIR*4;               //   262,144 f
    float* v1    = h1   + (size_t)B_*N_*K_;              //   786,432 f
    short* featsb = (short*)(v1 + (size_t)B_*N_*3*K_);   // 1,441,792 sh (2048x704)
    short* prep  = featsb + (size_t)2048*704;            //   733,184 sh
    short* w1T_1 = prep;
    short* w2T_1 = prep + 4096;
    short* w1T_2 = prep + 8192;
    short* w2T_2 = prep + 12288;
    short* w3T_2 = prep + 16384;
    short* wT0   = prep + 32768;     // [512][704]
    short* wT1   = prep + 393216;    // [512][512]
    short* w0T_1 = prep + 655360;    // [64][32]
    short* w0T_2 = prep + 657408;    // [64][32]
    short* w3T_1 = prep + 659456;    // [384][64]
    short* lcatT = prep + 684032;    // [384][128]
    short* hc2   = prep + PREP_TOTAL;     // 2048x64x64 bf16 = 16.78 MB
    short* h0bb  = hc2 + (size_t)2048*4096;   // 2048x512 bf16 = 2 MB
    short* h1bb  = h0bb + (size_t)2048*512;   // 2048x512 bf16 = 2 MB

    prep_kernel<<<(PREP_TOTAL + 255)/256, 256, 0, stream>>>(
        r1w1, r1w2, r2w1, r2w2, r2w3, mw0, mw1,
        r1w0, r2w0, r1w3, l0, l1, l2, prep);
    pass1x_kernel<<<B_*N_, 256, 0, stream>>>(pos, cell, wemb,
        w0T_1, r1b0, w1T_1, r1b1, w2T_1, r1b2, w3T_1, r1b3,
        w0T_2, r2b0, w1T_2, r2b1, w2T_2, r2b2,
        lcatT, timeg, geo4, hc2, h1, v1, featsb);
    pass2b_kernel<<<B_*N_, 256, 0, stream>>>(geo4, hc2,
        w3T_2, r2b3, mix2, h1, v1, featsb);
    dim3 g0(32, 8);
    gemm_mfma_kernel<<<g0, 256, 0, stream>>>(featsb, 704, wT0, 704, 704, mb0, h0bb, 512);
    gemm_mfma_kernel<<<g0, 256, 0, stream>>>(h0bb, 512, wT1, 512, 512, mb1, h1bb, 512);
    final3_kernel<<<B_*N_, 64, 0, stream>>>(h1bb, mw2, mb2, (float*)d_out);
}